// Round 13
// baseline (327.673 us; speedup 1.0000x reference)
//
#include <hip/hip_runtime.h>
#include <hip/hip_bf16.h>
#include <stdint.h>

#define NODES 50000
#define NEDGE 800000
#define TEDGE (NEDGE + NODES)

typedef unsigned short u16;
typedef unsigned int u32;
typedef unsigned long long u64;
typedef short s16x8 __attribute__((ext_vector_type(8)));
typedef float f32x4 __attribute__((ext_vector_type(4)));

__device__ __forceinline__ float bf2f(u16 v) {
  return __uint_as_float(((u32)v) << 16);
}
__device__ __forceinline__ u16 f2bf(float f) {
  u32 u = __float_as_uint(f);
  u32 r = (u + 0x7FFFu + ((u >> 16) & 1u)) >> 16;
  return (u16)r;
}
__device__ __forceinline__ float lo16f(u32 w) { return __uint_as_float(w << 16); }
__device__ __forceinline__ float hi16f(u32 w) { return __uint_as_float(w & 0xFFFF0000u); }
__device__ __forceinline__ float lrelu(float x) {
  return (x > 0.f) ? x : 0.2f * x;
}
__device__ __forceinline__ int clampn(int v) {
  return ((u32)v < NODES) ? v : 0;
}
// fb = "external float arrays are bf16"; else plain f32
__device__ __forceinline__ float load1(const void* p, size_t i, bool fb) {
  return fb ? bf2f(((const u16*)p)[i]) : ((const float*)p)[i];
}
// order-preserving float<->uint encoding for unsigned atomicMax
__device__ __forceinline__ u32 encf(float f) {
  u32 u = __float_as_uint(f);
  return (u & 0x80000000u) ? ~u : (u | 0x80000000u);
}
__device__ __forceinline__ float decf(u32 k) {
  u32 u = (k & 0x80000000u) ? (k & 0x7FFFFFFFu) : ~k;
  return __uint_as_float(u);
}

// ---------------- probes + deg/gm zero ----------------
// flags[0]: edge_index is int64; flags[1]: float arrays are bf16
// flags[8..31]: encoded per-head global maxes (3 layers)
__global__ __launch_bounds__(256) void k_probe(const int* __restrict__ ei,
                                               const u16* __restrict__ xs16,
                                               int* __restrict__ flags,
                                               int* __restrict__ deg) {
  int t = threadIdx.x;
  int g = blockIdx.x * 256 + t;
  if (g < NODES) deg[g] = 0;
  if (blockIdx.x == 0 && t >= 2 && t < 32) flags[t] = 0;
  if (blockIdx.x == 0 && t < 64) {
    int odd = 0, even = 0, big = 0;
#pragma unroll
    for (int k = 0; k < 4; ++k) {
      int idx = t + 64 * k;
      odd |= (ei[2 * idx + 1] != 0);
      even |= (ei[2 * idx] != 0);
      u32 ex = (xs16[2 * (t * 4 + k)] >> 7) & 0xFF;
      big += (ex >= 0x90);  // |v| >= 2^17: impossible for N(0,1) bf16
    }
    u64 bo = __ballot(odd);
    u64 be = __ballot(even);
#pragma unroll
    for (int off = 32; off >= 1; off >>= 1) big += __shfl_xor(big, off);
    if (t == 0) {
      flags[0] = (bo == 0ull && be != 0ull) ? 1 : 0;
      flags[1] = (big >= 8) ? 0 : 1;
    }
  }
}

// ---------------- W transpose: Wt[n][k] = W[k][n], bf16 out ----------------
__global__ __launch_bounds__(256) void k_tw(const void* __restrict__ W1,
                                            const void* __restrict__ W2,
                                            const void* __restrict__ W3,
                                            const int* __restrict__ flags,
                                            u16* __restrict__ wt1,
                                            u16* __restrict__ wt2,
                                            u16* __restrict__ wt3) {
  int id = blockIdx.x * 256 + threadIdx.x;
  bool fb = flags[1] != 0;
  if (id < 16384) {                       // W1: 128(K) x 128(N)
    int n = id >> 7, k = id & 127;
    wt1[n * 128 + k] = f2bf(load1(W1, (size_t)k * 128 + n, fb));
  } else if (id < 24576) {                // W2: 128(K) x 64(N)
    int r = id - 16384;
    int n = r >> 7, k = r & 127;
    wt2[n * 128 + k] = f2bf(load1(W2, (size_t)k * 64 + n, fb));
  } else if (id < 25600) {                // W3: 64(K) x 16(N)
    int r = id - 24576;
    int n = r >> 6, k = r & 63;
    wt3[n * 64 + k] = f2bf(load1(W3, (size_t)k * 16 + n, fb));
  }
}

// ---------------- CSR build (u16 payloads; 50k counters -> low contention) --

__global__ __launch_bounds__(256) void k_hist(const int* __restrict__ ei,
                                              const int* __restrict__ flags,
                                              int* deg, u16* __restrict__ rankarr,
                                              u16* __restrict__ src16,
                                              u16* __restrict__ dst16) {
  int e = blockIdx.x * 256 + threadIdx.x;
  if (e >= TEDGE) return;
  int d, s;
  if (e < NEDGE) {
    if (flags[0]) { s = ei[2 * e]; d = ei[2 * (NEDGE + e)]; }
    else { s = ei[e]; d = ei[NEDGE + e]; }
  } else {
    s = e - NEDGE; d = s;
  }
  s = clampn(s); d = clampn(d);
  src16[e] = (u16)s;
  dst16[e] = (u16)d;
  int r = atomicAdd(&deg[d], 1);
  rankarr[e] = (u16)min(r, 65535);
}

__global__ __launch_bounds__(1024) void k_scan(const int* __restrict__ deg,
                                               int* __restrict__ rowptr, int n) {
  int t = threadIdx.x, lane = t & 63, w = t >> 6;
  __shared__ int swave[16], soff[17];
  int carry = 0;
  for (int base = 0; base < n; base += 4096) {
    int i0 = base + t * 4;
    int v[4];
#pragma unroll
    for (int j = 0; j < 4; j++) { int i = i0 + j; v[j] = (i < n) ? deg[i] : 0; }
    int local = v[0] + v[1] + v[2] + v[3];
    int x = local;
#pragma unroll
    for (int off = 1; off < 64; off <<= 1) {
      int y = __shfl_up(x, off);
      if (lane >= off) x += y;
    }
    if (lane == 63) swave[w] = x;
    __syncthreads();
    if (w == 0) {
      int wv = (lane < 16) ? swave[lane] : 0;
#pragma unroll
      for (int off = 1; off < 16; off <<= 1) {
        int y = __shfl_up(wv, off);
        if (lane >= off) wv += y;
      }
      if (lane < 16) soff[lane + 1] = wv;
      if (lane == 0) soff[0] = 0;
    }
    __syncthreads();
    int run = carry + soff[w] + (x - local);
#pragma unroll
    for (int j = 0; j < 4; j++) {
      int i = i0 + j;
      if (i < n) rowptr[i] = run;
      run += v[j];
    }
    carry += soff[16];
    __syncthreads();
  }
  if (t == 0) rowptr[n] = carry;
}

__global__ __launch_bounds__(256) void k_scatter(const u16* __restrict__ src16,
                                                 const u16* __restrict__ dst16,
                                                 const int* __restrict__ rowptr,
                                                 const u16* __restrict__ rankarr,
                                                 u16* __restrict__ srcs) {
  int e = blockIdx.x * 256 + threadIdx.x;
  if (e >= TEDGE) return;
  int d = dst16[e];
  int pos = rowptr[d] + (int)rankarr[e];
  srcs[pos] = src16[e];
}

// ---------------- MFMA GEMM + fused attention dots (bf16) ----------
// h stored column-blocked in SL slices: h[s][node][N/SL] so each XCD's L2
// only touches its slice in k_agg. Fragment maps (verified):
// A[m=lane&15][k=quad*8+j]; B[k=quad*8+j][n=lane&15]; D[row=quad*4+reg][col=lane&15].

template <int K, int N, int H, int SL, bool XEXT>
__global__ __launch_bounds__(256) void k_gmfma(const void* __restrict__ xin,
                                               const u16* __restrict__ wtg,
                                               const void* __restrict__ a_src,
                                               const void* __restrict__ a_dst,
                                               u16* __restrict__ hout,
                                               float* __restrict__ asg,
                                               float* __restrict__ adg,
                                               u32* __restrict__ gm,
                                               const int* __restrict__ flags,
                                               int M) {
  constexpr int KP = K + 8;       // +8 bf16 pad: fragment reads 2-way only
  constexpr int NT = N / 16;
  constexpr int NTH = NT / H;     // MFMA n-tiles per head
  constexpr int KG = K / 8;
  constexpr int NS = N / SL;      // channels per slice
  __shared__ u16 wlds[N * KP];
  __shared__ u16 xlds[64 * KP];
  __shared__ u32 lmax[2 * H];
  int t = threadIdx.x;
  int row0 = blockIdx.x * 64;
  bool fb = flags[1] != 0;
  if (t < 2 * H) lmax[t] = 0;

  for (int i = t; i < N * KG; i += 256) {  // stage W^T (16B groups)
    int n = i / KG, kg = i % KG;
    *(uint4*)&wlds[n * KP + kg * 8] = *(const uint4*)(wtg + (size_t)n * K + kg * 8);
  }
  bool xbf = XEXT ? fb : true;
  for (int i = t; i < 64 * KG; i += 256) {  // stage x rows
    int r = i / KG, kg = i % KG;
    int grow = row0 + r;
    if (grow >= M) grow = M - 1;
    if (xbf) {
      *(uint4*)&xlds[r * KP + kg * 8] =
          *(const uint4*)((const u16*)xin + (size_t)grow * K + kg * 8);
    } else {
      const float* gp = (const float*)xin + (size_t)grow * K + kg * 8;
      float4 f0 = *(const float4*)gp, f1 = *(const float4*)(gp + 4);
      *(ushort4*)&xlds[r * KP + kg * 8] =
          make_ushort4(f2bf(f0.x), f2bf(f0.y), f2bf(f0.z), f2bf(f0.w));
      *(ushort4*)&xlds[r * KP + kg * 8 + 4] =
          make_ushort4(f2bf(f1.x), f2bf(f1.y), f2bf(f1.z), f2bf(f1.w));
    }
  }
  __syncthreads();

  int lane = t & 63, w = t >> 6;
  int lrow = lane & 15, quad = lane >> 4;
  f32x4 acc[NT];
#pragma unroll
  for (int nt = 0; nt < NT; ++nt) acc[nt] = (f32x4){0.f, 0.f, 0.f, 0.f};

  const u16* xbase = xlds + (w * 16 + lrow) * KP + quad * 8;
  const u16* wbase = wlds + lrow * KP + quad * 8;
#pragma unroll
  for (int ks = 0; ks < K / 32; ++ks) {
    s16x8 a = *(const s16x8*)(xbase + ks * 32);
#pragma unroll
    for (int nt = 0; nt < NT; ++nt) {
      s16x8 b = *(const s16x8*)(wbase + (size_t)nt * 16 * KP + ks * 32);
      acc[nt] = __builtin_amdgcn_mfma_f32_16x16x32_bf16(a, b, acc[nt], 0, 0, 0);
    }
  }

  // store h (slice-blocked) + fused attention dots
  float avs[NT], avd[NT];
#pragma unroll
  for (int nt = 0; nt < NT; ++nt) {
    avs[nt] = load1(a_src, nt * 16 + lrow, fb);
    avd[nt] = load1(a_dst, nt * 16 + lrow, fb);
  }
  int baserow = row0 + w * 16 + quad * 4;
#pragma unroll
  for (int r = 0; r < 4; ++r) {
    int grow = baserow + r;
    float ps[H], pd[H];
#pragma unroll
    for (int h = 0; h < H; ++h) {
      ps[h] = 0.f; pd[h] = 0.f;
#pragma unroll
      for (int i = 0; i < NTH; ++i) {
        int nt = h * NTH + i;
        ps[h] += acc[nt][r] * avs[nt];
        pd[h] += acc[nt][r] * avd[nt];
      }
    }
#pragma unroll
    for (int m = 1; m < 16; m <<= 1) {
#pragma unroll
      for (int h = 0; h < H; ++h) {
        ps[h] += __shfl_xor(ps[h], m);
        pd[h] += __shfl_xor(pd[h], m);
      }
    }
    if (grow < M) {
#pragma unroll
      for (int nt = 0; nt < NT; ++nt) {
        constexpr int TPS = NS / 16;  // tiles per slice
        int sl = nt / TPS;
        int lc = (nt % TPS) * 16 + lrow;
        hout[((size_t)sl * M + grow) * NS + lc] = f2bf(acc[nt][r]);
      }
#pragma unroll
      for (int h = 0; h < H; ++h) {
        if (lrow == h) {
          asg[grow * H + h] = ps[h];
          adg[grow * H + h] = pd[h];
          atomicMax(&lmax[h], encf(ps[h]));
          atomicMax(&lmax[H + h], encf(pd[h]));
        }
      }
    }
  }
  __syncthreads();
  if (t < 2 * H) atomicMax(&gm[t], lmax[t]);
}

// ---------------- fused softmax + aggregation (XCD-sliced) ----------------
// 2 nodes per wave (32 lanes each), 8 nodes per block. SL slices: blockIdx
// bit2 picks slice so (under %8 round-robin dispatch) XCDs 0-3 gather only
// slice 0 and XCDs 4-7 slice 1 -> per-XCD L2 working set halves. Each slice
// stages only its own H/SL heads and writes its channel half. Softmax with
// global upper bound M is exact (shift invariance); denominators are
// recomputed identically per slice (no communication).

template <int H, int C, int SL, bool RELU, bool FINAL>
__global__ __launch_bounds__(256) void k_agg(const u16* __restrict__ hbuf,
                                             const float* __restrict__ asg,
                                             const float* __restrict__ adg,
                                             const int* __restrict__ rowptr,
                                             const u16* __restrict__ srcs,
                                             const void* __restrict__ bias,
                                             const int* __restrict__ flags,
                                             const u32* __restrict__ gm,
                                             void* __restrict__ outp, int n) {
  constexpr int HC = H * C;
  constexpr int HCS = HC / SL;            // channels per slice
  constexpr int HH = H / SL;              // heads per slice
  constexpr int L = HCS / 8;              // lanes per edge row
  constexpr int EPN = 32 / L;             // edges per group (per node half)
  constexpr int UN = (4 * EPN <= 32) ? 4 : 2;  // groups in flight
  __shared__ u16 lds_s[4][64];
  __shared__ float lds_e[4][64][HH];
  int lane = threadIdx.x & 63;
  int w = threadIdx.x >> 6;
  int nh = lane >> 5;                     // node half within wave
  int hl = lane & 31;                     // lane within half
  int b = blockIdx.x;
  int slice, ng;
  if (SL == 1) { slice = 0; ng = b; }
  else { slice = (b >> 2) & 1; ng = ((b >> 3) << 2) | (b & 3); }
  int node = ng * 8 + w * 2 + nh;
  if (node >= n) node = n - 1;            // duplicate benign writes at tail
  bool fb = flags[1] != 0;
  int start = rowptr[node], end = rowptr[node + 1];
  if (end < start || end - start > TEDGE) { start = 0; end = 0; }

  int h0 = slice * HH;                    // first global head of this slice
  float adh[HH], M[HH];
#pragma unroll
  for (int j = 0; j < HH; ++j) {
    adh[j] = adg[node * H + h0 + j];
    M[j] = lrelu(decf(gm[h0 + j]) + decf(gm[H + h0 + j]));
  }

  int sub = hl / L;                       // edge slot within group
  int cl = hl & (L - 1);
  int ch0 = cl * 8;                       // within-slice channel
  int mh = ch0 / C;                       // head within slice (slice*HCS % C == 0)
  const u16* hbs = hbuf + (size_t)slice * n * HCS;

  float den[HH];
#pragma unroll
  for (int j = 0; j < HH; ++j) den[j] = 0.f;
  float acc[UN][8];
#pragma unroll
  for (int u = 0; u < UN; ++u)
#pragma unroll
    for (int i = 0; i < 8; ++i) acc[u][i] = 0.f;

  for (int chunk = start; chunk < end; chunk += 32) {
    int e = chunk + hl;
    int s = 0;
    float ee[HH];
#pragma unroll
    for (int j = 0; j < HH; ++j) ee[j] = 0.f;
    if (e < end) {
      s = srcs[e];
      float av[H];
      if (H == 4) { float4 t4 = *(const float4*)(asg + s * 4);
        av[0] = t4.x; av[1] = t4.y; av[H > 2 ? 2 : 0] = t4.z; av[H > 3 ? 3 : 0] = t4.w; }
      else if (H == 2) { float2 t2 = *(const float2*)(asg + s * 2); av[0] = t2.x; av[1] = t2.y; }
      else av[0] = asg[s];
#pragma unroll
      for (int j = 0; j < HH; ++j) {
        float x = __expf(lrelu(av[h0 + j] + adh[j]) - M[j]);  // arg <= 0 by bound
        ee[j] = x;
        den[j] += x;
      }
    }
    __builtin_amdgcn_wave_barrier();  // prior reads done before overwrite
    lds_s[w][lane] = (u16)s;
#pragma unroll
    for (int j = 0; j < HH; ++j) lds_e[w][lane][j] = ee[j];
    __builtin_amdgcn_wave_barrier();

    int base = nh * 32;
    int cn = min(32, end - chunk);
    for (int j = 0; j < cn; j += UN * EPN) {  // staged slots zero-padded
      int sx[UN];
      float ax[UN];
#pragma unroll
      for (int u = 0; u < UN; ++u) {
        int ei_ = base + j + u * EPN + sub;
        sx[u] = lds_s[w][ei_];
        ax[u] = lds_e[w][ei_][mh];
      }
#pragma unroll
      for (int u = 0; u < UN; ++u) {
        uint4 v = *(const uint4*)(hbs + (size_t)sx[u] * HCS + ch0);
        acc[u][0] += ax[u] * lo16f(v.x); acc[u][1] += ax[u] * hi16f(v.x);
        acc[u][2] += ax[u] * lo16f(v.y); acc[u][3] += ax[u] * hi16f(v.y);
        acc[u][4] += ax[u] * lo16f(v.z); acc[u][5] += ax[u] * hi16f(v.z);
        acc[u][6] += ax[u] * lo16f(v.w); acc[u][7] += ax[u] * hi16f(v.w);
      }
    }
  }

  // reduce denominators within the 32-lane half
#pragma unroll
  for (int m = 16; m >= 1; m >>= 1) {
#pragma unroll
    for (int j = 0; j < HH; ++j) den[j] += __shfl_xor(den[j], m);
  }
  // combine groups, then reduce channel accumulators across subs (within half)
  float tt[8];
#pragma unroll
  for (int i = 0; i < 8; ++i) {
    tt[i] = acc[0][i];
#pragma unroll
    for (int u = 1; u < UN; ++u) tt[i] += acc[u][i];
  }
#pragma unroll
  for (int m = L; m < 32; m <<= 1) {
#pragma unroll
    for (int i = 0; i < 8; ++i) tt[i] += __shfl_xor(tt[i], m);
  }

  if (sub == 0) {
    int gch = slice * HCS + ch0;          // global channel base
    float inv = 1.f / (den[mh] + 1e-16f);
    float o[8];
#pragma unroll
    for (int i = 0; i < 8; ++i) {
      o[i] = tt[i] * inv + load1(bias, gch + i, fb);
      if (RELU) o[i] = fmaxf(o[i], 0.f);
    }
    bool obf = FINAL ? fb : true;
    if (obf) {
      uint4 pk;
      pk.x = (u32)f2bf(o[0]) | ((u32)f2bf(o[1]) << 16);
      pk.y = (u32)f2bf(o[2]) | ((u32)f2bf(o[3]) << 16);
      pk.z = (u32)f2bf(o[4]) | ((u32)f2bf(o[5]) << 16);
      pk.w = (u32)f2bf(o[6]) | ((u32)f2bf(o[7]) << 16);
      *(uint4*)((u16*)outp + (size_t)node * HC + gch) = pk;
    } else {
      float* op = (float*)outp + (size_t)node * HC + gch;
      *(float4*)op = make_float4(o[0], o[1], o[2], o[3]);
      *(float4*)(op + 4) = make_float4(o[4], o[5], o[6], o[7]);
    }
  }
}

// ---------------- launch ----------------

extern "C" void kernel_launch(void* const* d_in, const int* in_sizes, int n_in,
                              void* d_out, int out_size, void* d_ws, size_t ws_size,
                              hipStream_t stream) {
  const void* x   = d_in[0];
  const int* ei   = (const int*)d_in[1];
  const void* W1  = d_in[2];
  const void* as1 = d_in[3];
  const void* ad1 = d_in[4];
  const void* b1  = d_in[5];
  const void* W2  = d_in[6];
  const void* as2 = d_in[7];
  const void* ad2 = d_in[8];
  const void* b2  = d_in[9];
  const void* W3  = d_in[10];
  const void* as3 = d_in[11];
  const void* ad3 = d_in[12];
  const void* b3  = d_in[13];

  char* w = (char*)d_ws;
  auto alloc = [&](size_t bytes) {
    char* p = w;
    w += (bytes + 255) & ~(size_t)255;
    return p;
  };
  int* flags    = (int*)alloc(256);
  int* deg      = (int*)alloc((size_t)NODES * 4);
  int* rowptr   = (int*)alloc((size_t)(NODES + 1) * 4);
  u16* rankarr  = (u16*)alloc((size_t)TEDGE * 2);
  u16* src16    = (u16*)alloc((size_t)TEDGE * 2);
  u16* dst16    = (u16*)alloc((size_t)TEDGE * 2);
  u16* srcs     = (u16*)alloc((size_t)TEDGE * 2);
  float* asg    = (float*)alloc((size_t)NODES * 4 * 4);
  float* adg    = (float*)alloc((size_t)NODES * 4 * 4);
  u16* wt1      = (u16*)alloc((size_t)128 * 128 * 2);
  u16* wt2      = (u16*)alloc((size_t)64 * 128 * 2);
  u16* wt3      = (u16*)alloc((size_t)16 * 64 * 2);
  u16* hbuf     = (u16*)alloc((size_t)NODES * 128 * 2);
  u16* obuf     = (u16*)alloc((size_t)NODES * 128 * 2);

  u32* gm1 = (u32*)(flags + 8);
  u32* gm2 = (u32*)(flags + 16);
  u32* gm3 = (u32*)(flags + 24);

  // probes + zeroing + weight transpose + CSR build
  k_probe<<<(NODES + 255) / 256, 256, 0, stream>>>(ei, (const u16*)x, flags, deg);
  k_tw<<<100, 256, 0, stream>>>(W1, W2, W3, flags, wt1, wt2, wt3);
  k_hist<<<(TEDGE + 255) / 256, 256, 0, stream>>>(ei, flags, deg, rankarr, src16, dst16);
  k_scan<<<1, 1024, 0, stream>>>(deg, rowptr, NODES);
  k_scatter<<<(TEDGE + 255) / 256, 256, 0, stream>>>(src16, dst16, rowptr, rankarr, srcs);

  int gblocks = (NODES + 63) / 64;
  int ngroups = (NODES + 7) / 8;              // 6250 node groups
  int ablocks2 = 8 * ((ngroups + 3) / 4);     // sliced grids (SL=2)
  int ablocks1 = ngroups;                     // unsliced (SL=1)

  // layer 1: 128 -> 4x32 concat, relu (sliced gather)
  k_gmfma<128, 128, 4, 2, true><<<gblocks, 256, 0, stream>>>(x, wt1, as1, ad1, hbuf, asg, adg, gm1, flags, NODES);
  k_agg<4, 32, 2, true, false><<<ablocks2, 256, 0, stream>>>(hbuf, asg, adg, rowptr, srcs, b1, flags, gm1, obuf, NODES);
  // layer 2: 128 -> 2x32 concat, relu (sliced gather)
  k_gmfma<128, 64, 2, 2, false><<<gblocks, 256, 0, stream>>>(obuf, wt2, as2, ad2, hbuf, asg, adg, gm2, flags, NODES);
  k_agg<2, 32, 2, true, false><<<ablocks2, 256, 0, stream>>>(hbuf, asg, adg, rowptr, srcs, b2, flags, gm2, obuf, NODES);
  // layer 3: 64 -> 1x16 mean(=identity), out dtype follows input dtype
  k_gmfma<64, 16, 1, 1, false><<<gblocks, 256, 0, stream>>>(obuf, wt3, as3, ad3, hbuf, asg, adg, gm3, flags, NODES);
  k_agg<1, 16, 1, false, true><<<ablocks1, 256, 0, stream>>>(hbuf, asg, adg, rowptr, srcs, b3, flags, gm3, d_out, NODES);
}

// Round 14
// 308.568 us; speedup vs baseline: 1.0619x; 1.0619x over previous
//
#include <hip/hip_runtime.h>
#include <hip/hip_bf16.h>
#include <stdint.h>

#define NODES 50000
#define NEDGE 800000
#define TEDGE (NEDGE + NODES)

typedef unsigned short u16;
typedef unsigned int u32;
typedef unsigned long long u64;
typedef short s16x8 __attribute__((ext_vector_type(8)));
typedef float f32x4 __attribute__((ext_vector_type(4)));

__device__ __forceinline__ float bf2f(u16 v) {
  return __uint_as_float(((u32)v) << 16);
}
__device__ __forceinline__ u16 f2bf(float f) {
  u32 u = __float_as_uint(f);
  u32 r = (u + 0x7FFFu + ((u >> 16) & 1u)) >> 16;
  return (u16)r;
}
__device__ __forceinline__ float lo16f(u32 w) { return __uint_as_float(w << 16); }
__device__ __forceinline__ float hi16f(u32 w) { return __uint_as_float(w & 0xFFFF0000u); }
__device__ __forceinline__ float lrelu(float x) {
  return (x > 0.f) ? x : 0.2f * x;
}
__device__ __forceinline__ int clampn(int v) {
  return ((u32)v < NODES) ? v : 0;
}
// fb = "external float arrays are bf16"; else plain f32
__device__ __forceinline__ float load1(const void* p, size_t i, bool fb) {
  return fb ? bf2f(((const u16*)p)[i]) : ((const float*)p)[i];
}
// order-preserving float<->uint encoding for unsigned atomicMax
__device__ __forceinline__ u32 encf(float f) {
  u32 u = __float_as_uint(f);
  return (u & 0x80000000u) ? ~u : (u | 0x80000000u);
}
__device__ __forceinline__ float decf(u32 k) {
  u32 u = (k & 0x80000000u) ? (k & 0x7FFFFFFFu) : ~k;
  return __uint_as_float(u);
}

// ---------------- probes + deg/gm zero ----------------
// flags[0]: edge_index is int64; flags[1]: float arrays are bf16
// flags[8..31]: encoded per-head global maxes (3 layers)
__global__ __launch_bounds__(256) void k_probe(const int* __restrict__ ei,
                                               const u16* __restrict__ xs16,
                                               int* __restrict__ flags,
                                               int* __restrict__ deg) {
  int t = threadIdx.x;
  int g = blockIdx.x * 256 + t;
  if (g < NODES) deg[g] = 0;
  if (blockIdx.x == 0 && t >= 2 && t < 32) flags[t] = 0;
  if (blockIdx.x == 0 && t < 64) {
    int odd = 0, even = 0, big = 0;
#pragma unroll
    for (int k = 0; k < 4; ++k) {
      int idx = t + 64 * k;
      odd |= (ei[2 * idx + 1] != 0);
      even |= (ei[2 * idx] != 0);
      u32 ex = (xs16[2 * (t * 4 + k)] >> 7) & 0xFF;
      big += (ex >= 0x90);  // |v| >= 2^17: impossible for N(0,1) bf16
    }
    u64 bo = __ballot(odd);
    u64 be = __ballot(even);
#pragma unroll
    for (int off = 32; off >= 1; off >>= 1) big += __shfl_xor(big, off);
    if (t == 0) {
      flags[0] = (bo == 0ull && be != 0ull) ? 1 : 0;
      flags[1] = (big >= 8) ? 0 : 1;
    }
  }
}

// ---------------- CSR build + fused weight transpose ----------------
// (u16 payloads; 50k counters -> ~17-way atomic contention, low)
// First 25600 threads additionally transpose W1/W2/W3 to bf16 Wt[n][k].

__global__ __launch_bounds__(256) void k_hist(const int* __restrict__ ei,
                                              const int* __restrict__ flags,
                                              int* deg, u16* __restrict__ rankarr,
                                              u16* __restrict__ src16,
                                              u16* __restrict__ dst16,
                                              const void* __restrict__ W1,
                                              const void* __restrict__ W2,
                                              const void* __restrict__ W3,
                                              u16* __restrict__ wt1,
                                              u16* __restrict__ wt2,
                                              u16* __restrict__ wt3) {
  int e = blockIdx.x * 256 + threadIdx.x;
  if (e >= TEDGE) return;
  bool fb = flags[1] != 0;
  if (e < 25600) {  // fused k_tw
    if (e < 16384) {                        // W1: 128(K) x 128(N)
      int n = e >> 7, k = e & 127;
      wt1[n * 128 + k] = f2bf(load1(W1, (size_t)k * 128 + n, fb));
    } else if (e < 24576) {                 // W2: 128(K) x 64(N)
      int r = e - 16384;
      int n = r >> 7, k = r & 127;
      wt2[n * 128 + k] = f2bf(load1(W2, (size_t)k * 64 + n, fb));
    } else {                                // W3: 64(K) x 16(N)
      int r = e - 24576;
      int n = r >> 6, k = r & 63;
      wt3[n * 64 + k] = f2bf(load1(W3, (size_t)k * 16 + n, fb));
    }
  }
  int d, s;
  if (e < NEDGE) {
    if (flags[0]) { s = ei[2 * e]; d = ei[2 * (NEDGE + e)]; }
    else { s = ei[e]; d = ei[NEDGE + e]; }
  } else {
    s = e - NEDGE; d = s;
  }
  s = clampn(s); d = clampn(d);
  src16[e] = (u16)s;
  dst16[e] = (u16)d;
  int r = atomicAdd(&deg[d], 1);
  rankarr[e] = (u16)min(r, 65535);
}

__global__ __launch_bounds__(1024) void k_scan(const int* __restrict__ deg,
                                               int* __restrict__ rowptr, int n) {
  int t = threadIdx.x, lane = t & 63, w = t >> 6;
  __shared__ int swave[16], soff[17];
  int carry = 0;
  for (int base = 0; base < n; base += 4096) {
    int i0 = base + t * 4;
    int v[4];
#pragma unroll
    for (int j = 0; j < 4; j++) { int i = i0 + j; v[j] = (i < n) ? deg[i] : 0; }
    int local = v[0] + v[1] + v[2] + v[3];
    int x = local;
#pragma unroll
    for (int off = 1; off < 64; off <<= 1) {
      int y = __shfl_up(x, off);
      if (lane >= off) x += y;
    }
    if (lane == 63) swave[w] = x;
    __syncthreads();
    if (w == 0) {
      int wv = (lane < 16) ? swave[lane] : 0;
#pragma unroll
      for (int off = 1; off < 16; off <<= 1) {
        int y = __shfl_up(wv, off);
        if (lane >= off) wv += y;
      }
      if (lane < 16) soff[lane + 1] = wv;
      if (lane == 0) soff[0] = 0;
    }
    __syncthreads();
    int run = carry + soff[w] + (x - local);
#pragma unroll
    for (int j = 0; j < 4; j++) {
      int i = i0 + j;
      if (i < n) rowptr[i] = run;
      run += v[j];
    }
    carry += soff[16];
    __syncthreads();
  }
  if (t == 0) rowptr[n] = carry;
}

__global__ __launch_bounds__(256) void k_scatter(const u16* __restrict__ src16,
                                                 const u16* __restrict__ dst16,
                                                 const int* __restrict__ rowptr,
                                                 const u16* __restrict__ rankarr,
                                                 u16* __restrict__ srcs) {
  int e = blockIdx.x * 256 + threadIdx.x;
  if (e >= TEDGE) return;
  int d = dst16[e];
  int pos = rowptr[d] + (int)rankarr[e];
  srcs[pos] = src16[e];
}

// ---------------- MFMA GEMM + fused attention dots (bf16) ----------
// h[M,N] = x[M,K] @ W[K,N]; asg/adg[n,h] = h.a_src/a_dst (f32 pre-rounding);
// global per-head maxes into gm. Wt pre-transposed [N][K]. 64 rows/block.
// Fragment maps (verified): A[m=lane&15][k=quad*8+j]; B[k=quad*8+j][n=lane&15];
// D[row=quad*4+reg][col=lane&15]. Heads concat along N: head(nt) = nt/NTH.

template <int K, int N, int H, bool XEXT>
__global__ __launch_bounds__(256) void k_gmfma(const void* __restrict__ xin,
                                               const u16* __restrict__ wtg,
                                               const void* __restrict__ a_src,
                                               const void* __restrict__ a_dst,
                                               u16* __restrict__ hout,
                                               float* __restrict__ asg,
                                               float* __restrict__ adg,
                                               u32* __restrict__ gm,
                                               const int* __restrict__ flags,
                                               int M) {
  constexpr int KP = K + 8;       // +8 bf16 pad: fragment reads 2-way only
  constexpr int NT = N / 16;
  constexpr int NTH = NT / H;     // MFMA n-tiles per head
  constexpr int KG = K / 8;
  __shared__ u16 wlds[N * KP];
  __shared__ u16 xlds[64 * KP];
  __shared__ u32 lmax[2 * H];
  int t = threadIdx.x;
  int row0 = blockIdx.x * 64;
  bool fb = flags[1] != 0;
  if (t < 2 * H) lmax[t] = 0;

  for (int i = t; i < N * KG; i += 256) {  // stage W^T (16B groups)
    int n = i / KG, kg = i % KG;
    *(uint4*)&wlds[n * KP + kg * 8] = *(const uint4*)(wtg + (size_t)n * K + kg * 8);
  }
  bool xbf = XEXT ? fb : true;
  for (int i = t; i < 64 * KG; i += 256) {  // stage x rows
    int r = i / KG, kg = i % KG;
    int grow = row0 + r;
    if (grow >= M) grow = M - 1;
    if (xbf) {
      *(uint4*)&xlds[r * KP + kg * 8] =
          *(const uint4*)((const u16*)xin + (size_t)grow * K + kg * 8);
    } else {
      const float* gp = (const float*)xin + (size_t)grow * K + kg * 8;
      float4 f0 = *(const float4*)gp, f1 = *(const float4*)(gp + 4);
      *(ushort4*)&xlds[r * KP + kg * 8] =
          make_ushort4(f2bf(f0.x), f2bf(f0.y), f2bf(f0.z), f2bf(f0.w));
      *(ushort4*)&xlds[r * KP + kg * 8 + 4] =
          make_ushort4(f2bf(f1.x), f2bf(f1.y), f2bf(f1.z), f2bf(f1.w));
    }
  }
  __syncthreads();

  int lane = t & 63, w = t >> 6;
  int lrow = lane & 15, quad = lane >> 4;
  f32x4 acc[NT];
#pragma unroll
  for (int nt = 0; nt < NT; ++nt) acc[nt] = (f32x4){0.f, 0.f, 0.f, 0.f};

  const u16* xbase = xlds + (w * 16 + lrow) * KP + quad * 8;
  const u16* wbase = wlds + lrow * KP + quad * 8;
#pragma unroll
  for (int ks = 0; ks < K / 32; ++ks) {
    s16x8 a = *(const s16x8*)(xbase + ks * 32);
#pragma unroll
    for (int nt = 0; nt < NT; ++nt) {
      s16x8 b = *(const s16x8*)(wbase + (size_t)nt * 16 * KP + ks * 32);
      acc[nt] = __builtin_amdgcn_mfma_f32_16x16x32_bf16(a, b, acc[nt], 0, 0, 0);
    }
  }

  // store h + fused attention dots
  float avs[NT], avd[NT];
#pragma unroll
  for (int nt = 0; nt < NT; ++nt) {
    avs[nt] = load1(a_src, nt * 16 + lrow, fb);
    avd[nt] = load1(a_dst, nt * 16 + lrow, fb);
  }
  int baserow = row0 + w * 16 + quad * 4;
#pragma unroll
  for (int r = 0; r < 4; ++r) {
    int grow = baserow + r;
    float ps[H], pd[H];
#pragma unroll
    for (int h = 0; h < H; ++h) {
      ps[h] = 0.f; pd[h] = 0.f;
#pragma unroll
      for (int i = 0; i < NTH; ++i) {
        int nt = h * NTH + i;
        ps[h] += acc[nt][r] * avs[nt];
        pd[h] += acc[nt][r] * avd[nt];
      }
    }
#pragma unroll
    for (int m = 1; m < 16; m <<= 1) {
#pragma unroll
      for (int h = 0; h < H; ++h) {
        ps[h] += __shfl_xor(ps[h], m);
        pd[h] += __shfl_xor(pd[h], m);
      }
    }
    if (grow < M) {
#pragma unroll
      for (int nt = 0; nt < NT; ++nt)
        hout[(size_t)grow * N + nt * 16 + lrow] = f2bf(acc[nt][r]);
#pragma unroll
      for (int h = 0; h < H; ++h) {
        if (lrow == h) {
          asg[grow * H + h] = ps[h];
          adg[grow * H + h] = pd[h];
          atomicMax(&lmax[h], encf(ps[h]));
          atomicMax(&lmax[H + h], encf(pd[h]));
        }
      }
    }
  }
  __syncthreads();
  if (t < 2 * H) atomicMax(&gm[t], lmax[t]);
}

// ---------------- fused softmax + aggregation ----------------
// 2 nodes per wave (32 lanes each), 8 nodes per block; one edge pass with
// global-bound softmax (alpha = exp(l-M)/sum exp(l-M), exact for any uniform
// upper bound M). Gather: L = HC/8 lanes per edge (8 bf16 ch, dwordx4),
// EPN = 32/L edges per group per node, UN groups in flight.
// NOTE (R6-R13 evidence): this kernel sits at a replicated-working-set floor
// (FETCH = 8 XCD x h-bytes at ~2.45 TB/s effective); edge-parallel, bucket-
// sort, and XCD-sliced variants all measured worse. Do not re-litigate
// without new counter evidence.

template <int H, int C, bool RELU, bool FINAL>
__global__ __launch_bounds__(256) void k_agg(const u16* __restrict__ hbuf,
                                             const float* __restrict__ asg,
                                             const float* __restrict__ adg,
                                             const int* __restrict__ rowptr,
                                             const u16* __restrict__ srcs,
                                             const void* __restrict__ bias,
                                             const int* __restrict__ flags,
                                             const u32* __restrict__ gm,
                                             void* __restrict__ outp, int n) {
  constexpr int HC = H * C;
  constexpr int L = HC / 8;               // lanes per edge row
  constexpr int EPN = 32 / L;             // edges per group (per node half)
  constexpr int UN = (4 * EPN <= 32) ? 4 : 2;  // groups in flight
  __shared__ u16 lds_s[4][64];
  __shared__ float lds_e[4][64][H];
  int lane = threadIdx.x & 63;
  int w = threadIdx.x >> 6;
  int nh = lane >> 5;                     // node half within wave
  int hl = lane & 31;                     // lane within half
  int node = blockIdx.x * 8 + w * 2 + nh;
  if (node >= n) node = n - 1;
  bool fb = flags[1] != 0;
  int start = rowptr[node], end = rowptr[node + 1];
  if (end < start || end - start > TEDGE) { start = 0; end = 0; }

  float adh[H], M[H];
#pragma unroll
  for (int h = 0; h < H; ++h) adh[h] = adg[node * H + h];
#pragma unroll
  for (int h = 0; h < H; ++h) M[h] = lrelu(decf(gm[h]) + decf(gm[H + h]));

  int sub = hl / L;                       // edge slot within group
  int cl = hl & (L - 1);
  int ch0 = cl * 8;
  int myhead = ch0 / C;
  int base = nh * 32;                     // this half's staging slots

  float den[H];
#pragma unroll
  for (int h = 0; h < H; ++h) den[h] = 0.f;
  float acc[UN][8];
#pragma unroll
  for (int u = 0; u < UN; ++u)
#pragma unroll
    for (int i = 0; i < 8; ++i) acc[u][i] = 0.f;

  for (int chunk = start; chunk < end; chunk += 32) {
    int e = chunk + hl;
    int s = 0;
    float ee[H];
#pragma unroll
    for (int h = 0; h < H; ++h) ee[h] = 0.f;
    if (e < end) {
      s = srcs[e];
      float av[H];
      if (H == 4) { float4 t4 = *(const float4*)(asg + s * 4);
        av[0] = t4.x; av[1] = t4.y; av[H > 2 ? 2 : 0] = t4.z; av[H > 3 ? 3 : 0] = t4.w; }
      else if (H == 2) { float2 t2 = *(const float2*)(asg + s * 2); av[0] = t2.x; av[1] = t2.y; }
      else av[0] = asg[s];
#pragma unroll
      for (int h = 0; h < H; ++h) {
        float x = __expf(lrelu(av[h] + adh[h]) - M[h]);  // arg <= 0 by bound
        ee[h] = x;
        den[h] += x;
      }
    }
    __builtin_amdgcn_wave_barrier();  // prior reads done before overwrite
    lds_s[w][lane] = (u16)s;
#pragma unroll
    for (int h = 0; h < H; ++h) lds_e[w][lane][h] = ee[h];
    __builtin_amdgcn_wave_barrier();

    int cn = min(32, end - chunk);
    for (int j = 0; j < cn; j += UN * EPN) {  // staged slots zero-padded
      int sx[UN];
      float ax[UN];
#pragma unroll
      for (int u = 0; u < UN; ++u) {
        int ei_ = base + j + u * EPN + sub;
        sx[u] = lds_s[w][ei_];
        ax[u] = lds_e[w][ei_][myhead];
      }
#pragma unroll
      for (int u = 0; u < UN; ++u) {
        uint4 v = *(const uint4*)(hbuf + (size_t)sx[u] * HC + ch0);
        acc[u][0] += ax[u] * lo16f(v.x); acc[u][1] += ax[u] * hi16f(v.x);
        acc[u][2] += ax[u] * lo16f(v.y); acc[u][3] += ax[u] * hi16f(v.y);
        acc[u][4] += ax[u] * lo16f(v.z); acc[u][5] += ax[u] * hi16f(v.z);
        acc[u][6] += ax[u] * lo16f(v.w); acc[u][7] += ax[u] * hi16f(v.w);
      }
    }
  }

  // reduce denominators within the 32-lane half
#pragma unroll
  for (int m = 16; m >= 1; m >>= 1) {
#pragma unroll
    for (int h = 0; h < H; ++h) den[h] += __shfl_xor(den[h], m);
  }
  // combine groups, then reduce channel accumulators across subs (within half)
  float tt[8];
#pragma unroll
  for (int i = 0; i < 8; ++i) {
    tt[i] = acc[0][i];
#pragma unroll
    for (int u = 1; u < UN; ++u) tt[i] += acc[u][i];
  }
#pragma unroll
  for (int m = L; m < 32; m <<= 1) {
#pragma unroll
    for (int i = 0; i < 8; ++i) tt[i] += __shfl_xor(tt[i], m);
  }

  if (sub == 0) {
    float inv = 1.f / (den[myhead] + 1e-16f);
    float o[8];
#pragma unroll
    for (int i = 0; i < 8; ++i) {
      o[i] = tt[i] * inv + load1(bias, ch0 + i, fb);
      if (RELU) o[i] = fmaxf(o[i], 0.f);
    }
    bool obf = FINAL ? fb : true;
    if (obf) {
      uint4 pk;
      pk.x = (u32)f2bf(o[0]) | ((u32)f2bf(o[1]) << 16);
      pk.y = (u32)f2bf(o[2]) | ((u32)f2bf(o[3]) << 16);
      pk.z = (u32)f2bf(o[4]) | ((u32)f2bf(o[5]) << 16);
      pk.w = (u32)f2bf(o[6]) | ((u32)f2bf(o[7]) << 16);
      *(uint4*)((u16*)outp + (size_t)node * HC + ch0) = pk;
    } else {
      float* op = (float*)outp + (size_t)node * HC + ch0;
      *(float4*)op = make_float4(o[0], o[1], o[2], o[3]);
      *(float4*)(op + 4) = make_float4(o[4], o[5], o[6], o[7]);
    }
  }
}

// ---------------- launch ----------------

extern "C" void kernel_launch(void* const* d_in, const int* in_sizes, int n_in,
                              void* d_out, int out_size, void* d_ws, size_t ws_size,
                              hipStream_t stream) {
  const void* x   = d_in[0];
  const int* ei   = (const int*)d_in[1];
  const void* W1  = d_in[2];
  const void* as1 = d_in[3];
  const void* ad1 = d_in[4];
  const void* b1  = d_in[5];
  const void* W2  = d_in[6];
  const void* as2 = d_in[7];
  const void* ad2 = d_in[8];
  const void* b2  = d_in[9];
  const void* W3  = d_in[10];
  const void* as3 = d_in[11];
  const void* ad3 = d_in[12];
  const void* b3  = d_in[13];

  char* w = (char*)d_ws;
  auto alloc = [&](size_t bytes) {
    char* p = w;
    w += (bytes + 255) & ~(size_t)255;
    return p;
  };
  int* flags    = (int*)alloc(256);
  int* deg      = (int*)alloc((size_t)NODES * 4);
  int* rowptr   = (int*)alloc((size_t)(NODES + 1) * 4);
  u16* rankarr  = (u16*)alloc((size_t)TEDGE * 2);
  u16* src16    = (u16*)alloc((size_t)TEDGE * 2);
  u16* dst16    = (u16*)alloc((size_t)TEDGE * 2);
  u16* srcs     = (u16*)alloc((size_t)TEDGE * 2);
  float* asg    = (float*)alloc((size_t)NODES * 4 * 4);
  float* adg    = (float*)alloc((size_t)NODES * 4 * 4);
  u16* wt1      = (u16*)alloc((size_t)128 * 128 * 2);
  u16* wt2      = (u16*)alloc((size_t)64 * 128 * 2);
  u16* wt3      = (u16*)alloc((size_t)16 * 64 * 2);
  u16* hbuf     = (u16*)alloc((size_t)NODES * 128 * 2);
  u16* obuf     = (u16*)alloc((size_t)NODES * 128 * 2);

  u32* gm1 = (u32*)(flags + 8);
  u32* gm2 = (u32*)(flags + 16);
  u32* gm3 = (u32*)(flags + 24);

  // probes + zeroing + CSR build (weight transpose fused into k_hist)
  k_probe<<<(NODES + 255) / 256, 256, 0, stream>>>(ei, (const u16*)x, flags, deg);
  k_hist<<<(TEDGE + 255) / 256, 256, 0, stream>>>(ei, flags, deg, rankarr, src16, dst16,
                                                  W1, W2, W3, wt1, wt2, wt3);
  k_scan<<<1, 1024, 0, stream>>>(deg, rowptr, NODES);
  k_scatter<<<(TEDGE + 255) / 256, 256, 0, stream>>>(src16, dst16, rowptr, rankarr, srcs);

  int gblocks = (NODES + 63) / 64;
  int ablocks = (NODES + 7) / 8;
  // layer 1: 128 -> 4x32 concat, relu
  k_gmfma<128, 128, 4, true><<<gblocks, 256, 0, stream>>>(x, wt1, as1, ad1, hbuf, asg, adg, gm1, flags, NODES);
  k_agg<4, 32, true, false><<<ablocks, 256, 0, stream>>>(hbuf, asg, adg, rowptr, srcs, b1, flags, gm1, obuf, NODES);
  // layer 2: 128 -> 2x32 concat, relu
  k_gmfma<128, 64, 2, false><<<gblocks, 256, 0, stream>>>(obuf, wt2, as2, ad2, hbuf, asg, adg, gm2, flags, NODES);
  k_agg<2, 32, true, false><<<ablocks, 256, 0, stream>>>(hbuf, asg, adg, rowptr, srcs, b2, flags, gm2, obuf, NODES);
  // layer 3: 64 -> 1x16 mean(=identity), out dtype follows input dtype
  k_gmfma<64, 16, 1, false><<<gblocks, 256, 0, stream>>>(obuf, wt3, as3, ad3, hbuf, asg, adg, gm3, flags, NODES);
  k_agg<1, 16, false, true><<<ablocks, 256, 0, stream>>>(hbuf, asg, adg, rowptr, srcs, b3, flags, gm3, d_out, NODES);
}